// Round 1
// baseline (1408.641 us; speedup 1.0000x reference)
//
#include <hip/hip_runtime.h>

#define TOK 4096
#define NPAT 65536
#define PDIM 512
#define DDIM 1024
#define CAP 1024
#define RSEL 160

typedef __attribute__((ext_vector_type(8))) short bf16x8;
typedef __attribute__((ext_vector_type(4))) float f32x4;
typedef unsigned short u16;
typedef unsigned int u32;
typedef unsigned long long u64;

__device__ __forceinline__ u16 f2b(float f) {
  union { float f; u32 u; } x; x.f = f;
  u32 r = x.u + 0x7FFFu + ((x.u >> 16) & 1u);   // RNE fp32->bf16
  return (u16)(r >> 16);
}

__device__ __forceinline__ void gl2lds16(const void* g, void* l) {
  __builtin_amdgcn_global_load_lds((const __attribute__((address_space(1))) u32*)g,
                                   (__attribute__((address_space(3))) u32*)l, 16, 0, 0);
}

__device__ __forceinline__ u32 fkey(float f) {  // monotonic float->uint
  u32 u = __float_as_uint(f);
  u ^= (u >> 31) ? 0xFFFFFFFFu : 0x80000000u;
  return u;
}

// ---- pattern row norms + normalized bf16 copy --------------------------------
__global__ __launch_bounds__(256) void k_patnorm(const float* __restrict__ pat,
                                                 u16* __restrict__ pnb,
                                                 float* __restrict__ prn) {
  int row = blockIdx.x * 4 + (threadIdx.x >> 6);
  int lane = threadIdx.x & 63;
  const float* p = pat + (size_t)row * PDIM + lane * 8;
  float4 v0 = *(const float4*)p;
  float4 v1 = *(const float4*)(p + 4);
  float s = v0.x*v0.x + v0.y*v0.y + v0.z*v0.z + v0.w*v0.w
          + v1.x*v1.x + v1.y*v1.y + v1.z*v1.z + v1.w*v1.w;
  #pragma unroll
  for (int m = 1; m < 64; m <<= 1) s += __shfl_xor(s, m);
  float rn = 1.0f / fmaxf(sqrtf(s), 1e-8f);
  if (lane == 0) prn[row] = rn;
  uint4 o;
  o.x = (u32)f2b(v0.x*rn) | ((u32)f2b(v0.y*rn) << 16);
  o.y = (u32)f2b(v0.z*rn) | ((u32)f2b(v0.w*rn) << 16);
  o.z = (u32)f2b(v1.x*rn) | ((u32)f2b(v1.y*rn) << 16);
  o.w = (u32)f2b(v1.z*rn) | ((u32)f2b(v1.w*rn) << 16);
  *(uint4*)(pnb + (size_t)row * PDIM + lane * 8) = o;
}

__global__ __launch_bounds__(256) void k_zero(int* __restrict__ p, int n) {
  int i = blockIdx.x * 256 + threadIdx.x;
  if (i < n) p[i] = 0;
}

__global__ __launch_bounds__(256) void k_tobf16(const float* __restrict__ s,
                                                u16* __restrict__ d, int n) {
  int i = blockIdx.x * 256 + threadIdx.x;
  if (i < n) d[i] = f2b(s[i]);
}

// ---- fp32 encoder GEMM: enc[T,P] = x[T,D] @ enc_w[P,D]^T + enc_b -------------
__global__ __launch_bounds__(256) void k_enc(const float* __restrict__ x,
                                             const float* __restrict__ ew,
                                             const float* __restrict__ eb,
                                             float* __restrict__ enc) {
  __shared__ float As[64 * 20];   // [m][k] stride 20
  __shared__ float Bs[16 * 68];   // [k][n] stride 68
  const int bm = blockIdx.x, bn = blockIdx.y;
  const int tid = threadIdx.x;
  const int tx = tid & 15, ty = tid >> 4;
  const int lr = tid >> 2, lq = tid & 3;
  float acc[4][4] = {};
  const float* ga = x  + (size_t)(bm * 64 + lr) * DDIM + lq * 4;
  const float* gb = ew + (size_t)(bn * 64 + lr) * DDIM + lq * 4;
  for (int kt = 0; kt < 64; ++kt) {
    float4 av = *(const float4*)(ga + kt * 16);
    float4 bv = *(const float4*)(gb + kt * 16);
    __syncthreads();
    *(float4*)&As[lr * 20 + lq * 4] = av;
    Bs[(lq * 4 + 0) * 68 + lr] = bv.x;
    Bs[(lq * 4 + 1) * 68 + lr] = bv.y;
    Bs[(lq * 4 + 2) * 68 + lr] = bv.z;
    Bs[(lq * 4 + 3) * 68 + lr] = bv.w;
    __syncthreads();
    #pragma unroll
    for (int k = 0; k < 16; ++k) {
      float4 b4 = *(const float4*)&Bs[k * 68 + tx * 4];
      float a0 = As[(ty * 4 + 0) * 20 + k];
      float a1 = As[(ty * 4 + 1) * 20 + k];
      float a2 = As[(ty * 4 + 2) * 20 + k];
      float a3 = As[(ty * 4 + 3) * 20 + k];
      acc[0][0] += a0*b4.x; acc[0][1] += a0*b4.y; acc[0][2] += a0*b4.z; acc[0][3] += a0*b4.w;
      acc[1][0] += a1*b4.x; acc[1][1] += a1*b4.y; acc[1][2] += a1*b4.z; acc[1][3] += a1*b4.w;
      acc[2][0] += a2*b4.x; acc[2][1] += a2*b4.y; acc[2][2] += a2*b4.z; acc[2][3] += a2*b4.w;
      acc[3][0] += a3*b4.x; acc[3][1] += a3*b4.y; acc[3][2] += a3*b4.z; acc[3][3] += a3*b4.w;
    }
  }
  const float4 bb = *(const float4*)&eb[bn * 64 + tx * 4];
  #pragma unroll
  for (int i = 0; i < 4; ++i) {
    float4 o;
    o.x = acc[i][0] + bb.x; o.y = acc[i][1] + bb.y;
    o.z = acc[i][2] + bb.z; o.w = acc[i][3] + bb.w;
    *(float4*)&enc[(size_t)(bm * 64 + ty * 4 + i) * PDIM + bn * 64 + tx * 4] = o;
  }
}

// ---- normalize enc rows: fp32 copy + bf16 copy -------------------------------
__global__ __launch_bounds__(256) void k_encnorm(const float* __restrict__ enc,
                                                 float* __restrict__ encn,
                                                 u16* __restrict__ encnb) {
  int row = blockIdx.x * 4 + (threadIdx.x >> 6);
  int lane = threadIdx.x & 63;
  const float* p = enc + (size_t)row * PDIM + lane * 8;
  float4 v0 = *(const float4*)p;
  float4 v1 = *(const float4*)(p + 4);
  float s = v0.x*v0.x + v0.y*v0.y + v0.z*v0.z + v0.w*v0.w
          + v1.x*v1.x + v1.y*v1.y + v1.z*v1.z + v1.w*v1.w;
  #pragma unroll
  for (int m = 1; m < 64; m <<= 1) s += __shfl_xor(s, m);
  float rn = 1.0f / fmaxf(sqrtf(s), 1e-8f);
  float4 n0 = {v0.x*rn, v0.y*rn, v0.z*rn, v0.w*rn};
  float4 n1 = {v1.x*rn, v1.y*rn, v1.z*rn, v1.w*rn};
  float* q = encn + (size_t)row * PDIM + lane * 8;
  *(float4*)q = n0;
  *(float4*)(q + 4) = n1;
  uint4 o;
  o.x = (u32)f2b(n0.x) | ((u32)f2b(n0.y) << 16);
  o.y = (u32)f2b(n0.z) | ((u32)f2b(n0.w) << 16);
  o.z = (u32)f2b(n1.x) | ((u32)f2b(n1.y) << 16);
  o.w = (u32)f2b(n1.z) | ((u32)f2b(n1.w) << 16);
  *(uint4*)(encnb + (size_t)row * PDIM + lane * 8) = o;
}

// ---- coarse sim (bf16 MFMA) + threshold candidate push -----------------------
// A: encnb [4096,512] bf16, B: pnb [65536,512] bf16, TN layout, K=512
__global__ __launch_bounds__(256) void k_sim(const u16* __restrict__ A,
                                             const u16* __restrict__ B,
                                             int* __restrict__ cnt,
                                             float* __restrict__ cval,
                                             int* __restrict__ cidx) {
  __shared__ __align__(16) u16 As[128 * 32];
  __shared__ __align__(16) u16 Bs[128 * 32];
  const int bm = blockIdx.x, bn = blockIdx.y;
  const int tid = threadIdx.x, lane = tid & 63, w = tid >> 6;
  const int wm = w >> 1, wn = w & 1;
  f32x4 acc[4][4];
  #pragma unroll
  for (int i = 0; i < 4; ++i)
    #pragma unroll
    for (int j = 0; j < 4; ++j) acc[i][j] = (f32x4){0.f, 0.f, 0.f, 0.f};

  const int c0 = w * 2, c1 = w * 2 + 1;
  const int lrow = lane >> 2, lk = (lane & 3) * 8;
  const u16* gA0 = A + (size_t)(bm * 128 + c0 * 16 + lrow) * PDIM + lk;
  const u16* gA1 = A + (size_t)(bm * 128 + c1 * 16 + lrow) * PDIM + lk;
  const u16* gB0 = B + (size_t)(bn * 128 + c0 * 16 + lrow) * PDIM + lk;
  const u16* gB1 = B + (size_t)(bn * 128 + c1 * 16 + lrow) * PDIM + lk;
  u16* lA0 = &As[c0 * 512]; u16* lA1 = &As[c1 * 512];
  u16* lB0 = &Bs[c0 * 512]; u16* lB1 = &Bs[c1 * 512];
  const int fm = (lane & 15) * 32 + (lane >> 4) * 8;

  for (int kt = 0; kt < 16; ++kt) {
    gl2lds16(gA0 + kt * 32, lA0);
    gl2lds16(gA1 + kt * 32, lA1);
    gl2lds16(gB0 + kt * 32, lB0);
    gl2lds16(gB1 + kt * 32, lB1);
    __syncthreads();
    bf16x8 af[4], bf[4];
    #pragma unroll
    for (int i = 0; i < 4; ++i) {
      af[i] = *(const bf16x8*)&As[(wm * 64 + i * 16) * 32 + fm];
      bf[i] = *(const bf16x8*)&Bs[(wn * 64 + i * 16) * 32 + fm];
    }
    #pragma unroll
    for (int i = 0; i < 4; ++i)
      #pragma unroll
      for (int j = 0; j < 4; ++j)
        acc[i][j] = __builtin_amdgcn_mfma_f32_16x16x32_bf16(af[i], bf[j], acc[i][j], 0, 0, 0);
    __syncthreads();
  }

  const float THR = 0.11f;  // rank-128 cut ~0.1276; Binom mean above THR ~420, cap 1024
  #pragma unroll
  for (int i = 0; i < 4; ++i) {
    int tbase = bm * 128 + wm * 64 + i * 16 + ((lane >> 4) << 2);
    #pragma unroll
    for (int j = 0; j < 4; ++j) {
      int pc = bn * 128 + wn * 64 + j * 16 + (lane & 15);
      #pragma unroll
      for (int r = 0; r < 4; ++r) {
        float v = acc[i][j][r];
        if (v > THR) {
          int tt = tbase + r;
          int pos = atomicAdd(&cnt[tt], 1);
          if (pos < CAP) {
            cval[(size_t)tt * CAP + pos] = v;
            cidx[(size_t)tt * CAP + pos] = pc;
          }
        }
      }
    }
  }
}

// ---- per-token: coarse sort -> top-160 -> fp32 rerank -> exact top-128 -> mean
__global__ __launch_bounds__(256) void k_select(const float* __restrict__ pat,
                                                const float* __restrict__ prn,
                                                const float* __restrict__ encn,
                                                const int* __restrict__ cnt,
                                                const float* __restrict__ cval,
                                                const int* __restrict__ cidx,
                                                u16* __restrict__ meanb) {
  __shared__ u64 keys[CAP];        // 8 KB
  __shared__ float fs[RSEL];
  __shared__ int fidx[RSEL];
  __shared__ u64 keys2[256];       // 2 KB
  __shared__ float wsum[4][PDIM];  // 8 KB
  const int t = blockIdx.x;
  const int tid = threadIdx.x;
  const int lane = tid & 63;
  const int w = tid >> 6;
  const int n = min(cnt[t], CAP);

  for (int i = tid; i < CAP; i += 256) {
    u64 key = ~0ull;
    if (i < n) {
      u32 uk = fkey(cval[(size_t)t * CAP + i]);
      key = ((u64)(~uk) << 32) | (u32)cidx[(size_t)t * CAP + i];  // val desc, idx asc
    }
    keys[i] = key;
  }
  __syncthreads();
  for (int k = 2; k <= CAP; k <<= 1) {
    for (int j = k >> 1; j > 0; j >>= 1) {
      for (int i = tid; i < CAP; i += 256) {
        int ixj = i ^ j;
        if (ixj > i) {
          u64 a = keys[i], b = keys[ixj];
          if ((a > b) == ((i & k) == 0)) { keys[i] = b; keys[ixj] = a; }
        }
      }
      __syncthreads();
    }
  }
  if (tid < RSEL) fidx[tid] = (int)(u32)(keys[tid] & 0xFFFFFFFFull);
  __syncthreads();

  const float* er = encn + (size_t)t * PDIM + lane * 8;
  float4 e0 = *(const float4*)er;
  float4 e1 = *(const float4*)(er + 4);

  // fp32 rerank of the coarse top-160 (one wave per candidate, round-robin)
  for (int c = w; c < RSEL; c += 4) {
    int id = fidx[c];
    float dd = 0.0f;
    bool ok = ((u32)id < (u32)NPAT);
    if (ok) {
      const float* pr = pat + (size_t)id * PDIM + lane * 8;
      float4 p0 = *(const float4*)pr;
      float4 p1 = *(const float4*)(pr + 4);
      dd = p0.x*e0.x + p0.y*e0.y + p0.z*e0.z + p0.w*e0.w
         + p1.x*e1.x + p1.y*e1.y + p1.z*e1.z + p1.w*e1.w;
    }
    #pragma unroll
    for (int m = 1; m < 64; m <<= 1) dd += __shfl_xor(dd, m);
    if (lane == 0) fs[c] = ok ? dd * prn[id] : -1e30f;
  }
  __syncthreads();

  {
    u64 key = ~0ull;
    if (tid < RSEL) key = ((u64)(~fkey(fs[tid])) << 32) | (u32)fidx[tid];
    keys2[tid] = key;
  }
  __syncthreads();
  for (int k = 2; k <= 256; k <<= 1) {
    for (int j = k >> 1; j > 0; j >>= 1) {
      int ixj = tid ^ j;
      if (ixj > tid) {
        u64 a = keys2[tid], b = keys2[ixj];
        if ((a > b) == ((tid & k) == 0)) { keys2[tid] = b; keys2[ixj] = a; }
      }
      __syncthreads();
    }
  }

  // sum the 128 winners (exact set per fp32 values, ties by lower pattern idx)
  float4 s0 = {0,0,0,0}, s1 = {0,0,0,0};
  for (int c = w; c < 128; c += 4) {
    int id = (int)(u32)(keys2[c] & 0xFFFFFFFFull);
    if ((u32)id < (u32)NPAT) {
      const float* pr = pat + (size_t)id * PDIM + lane * 8;
      float4 p0 = *(const float4*)pr;
      float4 p1 = *(const float4*)(pr + 4);
      s0.x += p0.x; s0.y += p0.y; s0.z += p0.z; s0.w += p0.w;
      s1.x += p1.x; s1.y += p1.y; s1.z += p1.z; s1.w += p1.w;
    }
  }
  *(float4*)&wsum[w][lane * 8]     = s0;
  *(float4*)&wsum[w][lane * 8 + 4] = s1;
  __syncthreads();
  for (int dd = tid; dd < PDIM; dd += 256) {
    float m = (wsum[0][dd] + wsum[1][dd] + wsum[2][dd] + wsum[3][dd]) * (1.0f / 128.0f);
    meanb[(size_t)t * PDIM + dd] = f2b(m);
  }
}

// ---- decoder (bf16 MFMA): out = x + alpha*(mean @ dec_w^T + dec_b) -----------
__global__ __launch_bounds__(256) void k_dec(const u16* __restrict__ A,
                                             const u16* __restrict__ B,
                                             const float* __restrict__ x,
                                             const float* __restrict__ alpha,
                                             const float* __restrict__ db,
                                             float* __restrict__ out) {
  __shared__ __align__(16) u16 As[128 * 32];
  __shared__ __align__(16) u16 Bs[128 * 32];
  const int bm = blockIdx.x, bn = blockIdx.y;
  const int tid = threadIdx.x, lane = tid & 63, w = tid >> 6;
  const int wm = w >> 1, wn = w & 1;
  f32x4 acc[4][4];
  #pragma unroll
  for (int i = 0; i < 4; ++i)
    #pragma unroll
    for (int j = 0; j < 4; ++j) acc[i][j] = (f32x4){0.f, 0.f, 0.f, 0.f};

  const int c0 = w * 2, c1 = w * 2 + 1;
  const int lrow = lane >> 2, lk = (lane & 3) * 8;
  const u16* gA0 = A + (size_t)(bm * 128 + c0 * 16 + lrow) * PDIM + lk;
  const u16* gA1 = A + (size_t)(bm * 128 + c1 * 16 + lrow) * PDIM + lk;
  const u16* gB0 = B + (size_t)(bn * 128 + c0 * 16 + lrow) * PDIM + lk;
  const u16* gB1 = B + (size_t)(bn * 128 + c1 * 16 + lrow) * PDIM + lk;
  u16* lA0 = &As[c0 * 512]; u16* lA1 = &As[c1 * 512];
  u16* lB0 = &Bs[c0 * 512]; u16* lB1 = &Bs[c1 * 512];
  const int fm = (lane & 15) * 32 + (lane >> 4) * 8;

  for (int kt = 0; kt < 16; ++kt) {
    gl2lds16(gA0 + kt * 32, lA0);
    gl2lds16(gA1 + kt * 32, lA1);
    gl2lds16(gB0 + kt * 32, lB0);
    gl2lds16(gB1 + kt * 32, lB1);
    __syncthreads();
    bf16x8 af[4], bf[4];
    #pragma unroll
    for (int i = 0; i < 4; ++i) {
      af[i] = *(const bf16x8*)&As[(wm * 64 + i * 16) * 32 + fm];
      bf[i] = *(const bf16x8*)&Bs[(wn * 64 + i * 16) * 32 + fm];
    }
    #pragma unroll
    for (int i = 0; i < 4; ++i)
      #pragma unroll
      for (int j = 0; j < 4; ++j)
        acc[i][j] = __builtin_amdgcn_mfma_f32_16x16x32_bf16(af[i], bf[j], acc[i][j], 0, 0, 0);
    __syncthreads();
  }

  const float al = alpha[0];
  #pragma unroll
  for (int i = 0; i < 4; ++i) {
    int tbase = bm * 128 + wm * 64 + i * 16 + ((lane >> 4) << 2);
    #pragma unroll
    for (int j = 0; j < 4; ++j) {
      int dcol = bn * 128 + wn * 64 + j * 16 + (lane & 15);
      float bias = db[dcol];
      #pragma unroll
      for (int r = 0; r < 4; ++r) {
        int tt = tbase + r;
        size_t oi = (size_t)tt * DDIM + dcol;
        out[oi] = x[oi] + al * (acc[i][j][r] + bias);
      }
    }
  }
}

extern "C" void kernel_launch(void* const* d_in, const int* in_sizes, int n_in,
                              void* d_out, int out_size, void* d_ws, size_t ws_size,
                              hipStream_t stream) {
  const float* x     = (const float*)d_in[0];
  const float* pat   = (const float*)d_in[1];
  const float* alpha = (const float*)d_in[2];
  const float* enc_w = (const float*)d_in[3];
  const float* enc_b = (const float*)d_in[4];
  const float* dec_w = (const float*)d_in[5];
  const float* dec_b = (const float*)d_in[6];
  float* out = (float*)d_out;

  char* wsb = (char*)d_ws;
  size_t o = 0;
  auto alloc = [&](size_t bytes) -> void* {
    void* p = wsb + o;
    o += (bytes + 255) & ~(size_t)255;
    return p;
  };
  u16*   pnb    = (u16*)  alloc((size_t)NPAT * PDIM * 2);   // 64 MB
  float* prn    = (float*)alloc((size_t)NPAT * 4);          // 256 KB
  float* enc    = (float*)alloc((size_t)TOK * PDIM * 4);    // 8 MB
  float* encn   = (float*)alloc((size_t)TOK * PDIM * 4);    // 8 MB
  u16*   encnb  = (u16*)  alloc((size_t)TOK * PDIM * 2);    // 4 MB
  int*   ccnt   = (int*)  alloc((size_t)TOK * 4);           // 16 KB
  float* cvals  = (float*)alloc((size_t)TOK * CAP * 4);     // 16 MB
  int*   cids   = (int*)  alloc((size_t)TOK * CAP * 4);     // 16 MB
  u16*   meanb  = (u16*)  alloc((size_t)TOK * PDIM * 2);    // 4 MB
  u16*   decwb  = (u16*)  alloc((size_t)DDIM * PDIM * 2);   // 1 MB
  (void)ws_size; (void)in_sizes; (void)n_in; (void)out_size;

  k_patnorm<<<dim3(NPAT / 4), dim3(256), 0, stream>>>(pat, pnb, prn);
  k_zero<<<dim3(TOK / 256), dim3(256), 0, stream>>>(ccnt, TOK);
  k_tobf16<<<dim3((DDIM * PDIM) / 256), dim3(256), 0, stream>>>(dec_w, decwb, DDIM * PDIM);
  k_enc<<<dim3(TOK / 64, PDIM / 64), dim3(256), 0, stream>>>(x, enc_w, enc_b, enc);
  k_encnorm<<<dim3(TOK / 4), dim3(256), 0, stream>>>(enc, encn, encnb);
  k_sim<<<dim3(TOK / 128, NPAT / 128), dim3(256), 0, stream>>>(encnb, pnb, ccnt, cvals, cids);
  k_select<<<dim3(TOK), dim3(256), 0, stream>>>(pat, prn, encn, ccnt, cvals, cids, meanb);
  k_dec<<<dim3(TOK / 128, DDIM / 128), dim3(256), 0, stream>>>(meanb, decwb, x, alpha, dec_b, out);
}

// Round 2
// 1185.460 us; speedup vs baseline: 1.1883x; 1.1883x over previous
//
#include <hip/hip_runtime.h>
#include <hip/hip_fp8.h>

#define TOK 4096
#define NPAT 65536
#define PDIM 512
#define DDIM 1024
#define CAP 1024
#define RSEL 256

typedef __attribute__((ext_vector_type(8))) short bf16x8;
typedef __attribute__((ext_vector_type(4))) float f32x4;
typedef unsigned short u16;
typedef unsigned int u32;
typedef unsigned long long u64;

__device__ __forceinline__ u16 f2b(float f) {
  union { float f; u32 u; } x; x.f = f;
  u32 r = x.u + 0x7FFFu + ((x.u >> 16) & 1u);   // RNE fp32->bf16
  return (u16)(r >> 16);
}
__device__ __forceinline__ float b2f(u16 h) {
  union { u32 u; float f; } x; x.u = ((u32)h) << 16; return x.f;
}
__device__ __forceinline__ u32 f2f8(float v) {   // OCP e4m3, RNE+sat via HW
  __hip_fp8_e4m3 t(v);
  return (u32)(unsigned char)t.__x;
}

__device__ __forceinline__ void gl2lds16(const void* g, void* l) {
  __builtin_amdgcn_global_load_lds((const __attribute__((address_space(1))) u32*)g,
                                   (__attribute__((address_space(3))) u32*)l, 16, 0, 0);
}

__device__ __forceinline__ u32 fkey(float f) {  // monotonic float->uint
  u32 u = __float_as_uint(f);
  u ^= (u >> 31) ? 0xFFFFFFFFu : 0x80000000u;
  return u;
}

// ---- pattern row norms + normalized fp8 copy (scale 32) ----------------------
__global__ __launch_bounds__(256) void k_patnorm(const float* __restrict__ pat,
                                                 unsigned char* __restrict__ pnf8,
                                                 float* __restrict__ prn) {
  int row = blockIdx.x * 4 + (threadIdx.x >> 6);
  int lane = threadIdx.x & 63;
  const float* p = pat + (size_t)row * PDIM + lane * 8;
  float4 v0 = *(const float4*)p;
  float4 v1 = *(const float4*)(p + 4);
  float s = v0.x*v0.x + v0.y*v0.y + v0.z*v0.z + v0.w*v0.w
          + v1.x*v1.x + v1.y*v1.y + v1.z*v1.z + v1.w*v1.w;
  #pragma unroll
  for (int m = 1; m < 64; m <<= 1) s += __shfl_xor(s, m);
  float rn = 1.0f / fmaxf(sqrtf(s), 1e-8f);
  if (lane == 0) prn[row] = rn;
  float sc = rn * 32.0f;
  uint2 o;
  o.x = f2f8(v0.x*sc) | (f2f8(v0.y*sc) << 8) | (f2f8(v0.z*sc) << 16) | (f2f8(v0.w*sc) << 24);
  o.y = f2f8(v1.x*sc) | (f2f8(v1.y*sc) << 8) | (f2f8(v1.z*sc) << 16) | (f2f8(v1.w*sc) << 24);
  *(uint2*)(pnf8 + (size_t)row * PDIM + lane * 8) = o;
}

__global__ __launch_bounds__(256) void k_zero(int* __restrict__ p, int n) {
  int i = blockIdx.x * 256 + threadIdx.x;
  if (i < n) p[i] = 0;
}

__global__ __launch_bounds__(256) void k_tobf16(const float* __restrict__ s,
                                                u16* __restrict__ d, int n) {
  int i = blockIdx.x * 256 + threadIdx.x;
  if (i < n) d[i] = f2b(s[i]);
}

// ---- split fp32 -> bf16 hi/lo (float4 per thread) ----------------------------
__global__ __launch_bounds__(256) void k_split4(const float* __restrict__ s,
                                                u16* __restrict__ hi,
                                                u16* __restrict__ lo, int n4) {
  int i = blockIdx.x * 256 + threadIdx.x;
  if (i >= n4) return;
  float4 v = *(const float4*)(s + (size_t)i * 4);
  ushort4 h, l;
  h.x = f2b(v.x); l.x = f2b(v.x - b2f(h.x));
  h.y = f2b(v.y); l.y = f2b(v.y - b2f(h.y));
  h.z = f2b(v.z); l.z = f2b(v.z - b2f(h.z));
  h.w = f2b(v.w); l.w = f2b(v.w - b2f(h.w));
  *(ushort4*)(hi + (size_t)i * 4) = h;
  *(ushort4*)(lo + (size_t)i * 4) = l;
}

// ---- encoder via split-bf16 MFMA: enc = xh(wh+wl)^T + xl wh^T + eb -----------
// 64x128 tile, 3 phases over K=1024
__global__ __launch_bounds__(256) void k_enc3(const u16* __restrict__ xh,
                                              const u16* __restrict__ xl,
                                              const u16* __restrict__ wh,
                                              const u16* __restrict__ wl,
                                              const float* __restrict__ eb,
                                              float* __restrict__ enc) {
  __shared__ __align__(16) u16 As[64 * 32];
  __shared__ __align__(16) u16 Bs[128 * 32];
  const int bm = blockIdx.x, bn = blockIdx.y;
  const int tid = threadIdx.x, lane = tid & 63, w = tid >> 6;
  const int wm = w >> 1, wn = w & 1;
  f32x4 acc[2][4];
  #pragma unroll
  for (int i = 0; i < 2; ++i)
    #pragma unroll
    for (int j = 0; j < 4; ++j) acc[i][j] = (f32x4){0.f, 0.f, 0.f, 0.f};

  const int arow = tid >> 2, ael = (tid & 3) * 8;
  const int fm = (lane & 15) * 32 + (lane >> 4) * 8;
  const u16* APh[3] = {xh, xh, xl};
  const u16* BPh[3] = {wh, wl, wh};

  for (int ph = 0; ph < 3; ++ph) {
    const u16* Ag = APh[ph] + (size_t)(bm * 64 + arow) * DDIM + ael;
    const u16* Bg0 = BPh[ph] + (size_t)(bn * 128 + arow) * DDIM + ael;
    const u16* Bg1 = BPh[ph] + (size_t)(bn * 128 + 64 + arow) * DDIM + ael;
    for (int kt = 0; kt < 32; ++kt) {
      gl2lds16(Ag + kt * 32, As + (size_t)tid * 8);
      gl2lds16(Bg0 + kt * 32, Bs + (size_t)tid * 8);
      gl2lds16(Bg1 + kt * 32, Bs + (size_t)(tid + 256) * 8);
      __syncthreads();
      bf16x8 af[2], bf[4];
      #pragma unroll
      for (int i = 0; i < 2; ++i) af[i] = *(const bf16x8*)&As[(wm * 32 + i * 16) * 32 + fm];
      #pragma unroll
      for (int j = 0; j < 4; ++j) bf[j] = *(const bf16x8*)&Bs[(wn * 64 + j * 16) * 32 + fm];
      #pragma unroll
      for (int i = 0; i < 2; ++i)
        #pragma unroll
        for (int j = 0; j < 4; ++j)
          acc[i][j] = __builtin_amdgcn_mfma_f32_16x16x32_bf16(af[i], bf[j], acc[i][j], 0, 0, 0);
      __syncthreads();
    }
  }
  #pragma unroll
  for (int i = 0; i < 2; ++i) {
    int rbase = bm * 64 + wm * 32 + i * 16 + ((lane >> 4) << 2);
    #pragma unroll
    for (int j = 0; j < 4; ++j) {
      int col = bn * 128 + wn * 64 + j * 16 + (lane & 15);
      float bias = eb[col];
      #pragma unroll
      for (int r = 0; r < 4; ++r)
        enc[(size_t)(rbase + r) * PDIM + col] = acc[i][j][r] + bias;
    }
  }
}

// ---- normalize enc rows: fp32 copy + fp8 copy (scale 32) ---------------------
__global__ __launch_bounds__(256) void k_encnorm(const float* __restrict__ enc,
                                                 float* __restrict__ encn,
                                                 unsigned char* __restrict__ encf8) {
  int row = blockIdx.x * 4 + (threadIdx.x >> 6);
  int lane = threadIdx.x & 63;
  const float* p = enc + (size_t)row * PDIM + lane * 8;
  float4 v0 = *(const float4*)p;
  float4 v1 = *(const float4*)(p + 4);
  float s = v0.x*v0.x + v0.y*v0.y + v0.z*v0.z + v0.w*v0.w
          + v1.x*v1.x + v1.y*v1.y + v1.z*v1.z + v1.w*v1.w;
  #pragma unroll
  for (int m = 1; m < 64; m <<= 1) s += __shfl_xor(s, m);
  float rn = 1.0f / fmaxf(sqrtf(s), 1e-8f);
  float4 n0 = {v0.x*rn, v0.y*rn, v0.z*rn, v0.w*rn};
  float4 n1 = {v1.x*rn, v1.y*rn, v1.z*rn, v1.w*rn};
  float* q = encn + (size_t)row * PDIM + lane * 8;
  *(float4*)q = n0;
  *(float4*)(q + 4) = n1;
  uint2 o;
  o.x = f2f8(n0.x*32.f) | (f2f8(n0.y*32.f) << 8) | (f2f8(n0.z*32.f) << 16) | (f2f8(n0.w*32.f) << 24);
  o.y = f2f8(n1.x*32.f) | (f2f8(n1.y*32.f) << 8) | (f2f8(n1.z*32.f) << 16) | (f2f8(n1.w*32.f) << 24);
  *(uint2*)(encf8 + (size_t)row * PDIM + lane * 8) = o;
}

// ---- coarse sim: fp8 MFMA, A-resident-in-LDS, barrier-free K-loop ------------
// A: encf8 [4096][512], B: pnf8 [65536][512]. Block: 128 tokens x 4096 patterns.
// 512 thr / 8 waves; wave w owns 32 pattern-cols per 256-col pass; 16 passes.
__global__ __launch_bounds__(512, 4) void k_sim(const unsigned char* __restrict__ A,
                                                const unsigned char* __restrict__ B,
                                                int* __restrict__ cnt,
                                                float* __restrict__ cval,
                                                int* __restrict__ cidx) {
  __shared__ __align__(16) unsigned char As[65536];  // [16 kt][128 row][32 B]
  const int bm = blockIdx.x;
  const int nb0 = blockIdx.y * 4096;
  const int tid = threadIdx.x, lane = tid & 63, w = tid >> 6;

  // stage A-tile once: 64 KB, global_load_lds width-16
  {
    int row = (tid >> 1) & 127;
    int kt0 = tid >> 8;             // 0..1
    int c = (tid & 1) * 16;
    const unsigned char* g = A + (size_t)(bm * 128 + row) * PDIM + kt0 * 32 + c;
    #pragma unroll
    for (int s = 0; s < 8; ++s)
      gl2lds16(g + s * 64, &As[s * 8192 + tid * 16]);
  }

  f32x4 acc[8][2];
  #pragma unroll
  for (int m = 0; m < 8; ++m) {
    acc[m][0] = (f32x4){0.f, 0.f, 0.f, 0.f};
    acc[m][1] = (f32x4){0.f, 0.f, 0.f, 0.f};
  }
  const int baseA = (lane & 15) * 32 + (lane >> 4) * 8;
  const unsigned char* bp0 = B + (size_t)(nb0 + w * 32 + (lane & 15)) * PDIM + (lane >> 4) * 8;
  const unsigned char* bp1 = bp0 + 16 * PDIM;

  __syncthreads();   // A-tile ready; no barriers after this point

  long bnext0 = *(const long*)bp0;
  long bnext1 = *(const long*)bp1;
  const float THRS = 112.64f;   // 0.11 * 32 * 32

  for (int it = 0; it < 256; ++it) {
    const int kt = it & 15;
    long bc0 = bnext0, bc1 = bnext1;
    {
      long d = (kt == 15) ? (long)(256 * PDIM - 15 * 32) : 32;
      bp0 += d; bp1 += d;
      if (it < 255) { bnext0 = *(const long*)bp0; bnext1 = *(const long*)bp1; }
    }
    long a[8];
    #pragma unroll
    for (int m = 0; m < 8; ++m)
      a[m] = *(const long*)&As[kt * 4096 + m * 512 + baseA];
    #pragma unroll
    for (int m = 0; m < 8; ++m) {
      acc[m][0] = __builtin_amdgcn_mfma_f32_16x16x32_fp8_fp8(a[m], bc0, acc[m][0], 0, 0, 0);
      acc[m][1] = __builtin_amdgcn_mfma_f32_16x16x32_fp8_fp8(a[m], bc1, acc[m][1], 0, 0, 0);
    }
    if (kt == 15) {   // end of pass: threshold-push epilogue, reset acc
      int ncol = nb0 + (it >> 4) * 256 + w * 32;
      #pragma unroll
      for (int m = 0; m < 8; ++m) {
        int tokbase = bm * 128 + m * 16 + ((lane >> 4) << 2);
        #pragma unroll
        for (int j = 0; j < 2; ++j) {
          int pc = ncol + j * 16 + (lane & 15);
          #pragma unroll
          for (int r = 0; r < 4; ++r) {
            float v = acc[m][j][r];
            if (v > THRS) {
              int tt = tokbase + r;
              int pos = atomicAdd(&cnt[tt], 1);
              if (pos < CAP) {
                cval[(size_t)tt * CAP + pos] = v;
                cidx[(size_t)tt * CAP + pos] = pc;
              }
            }
            acc[m][j][r] = 0.f;
          }
        }
      }
    }
  }
}

// ---- per-token: sort candidates -> top-256 -> fp32 rerank -> top-128 -> mean -
__global__ __launch_bounds__(256) void k_select(const float* __restrict__ pat,
                                                const float* __restrict__ prn,
                                                const float* __restrict__ encn,
                                                const int* __restrict__ cnt,
                                                const float* __restrict__ cval,
                                                const int* __restrict__ cidx,
                                                u16* __restrict__ meanb) {
  __shared__ u64 keys[CAP];
  __shared__ float fs[RSEL];
  __shared__ int fidx[RSEL];
  __shared__ u64 keys2[256];
  __shared__ float wsum[4][PDIM];
  const int t = blockIdx.x;
  const int tid = threadIdx.x;
  const int lane = tid & 63;
  const int w = tid >> 6;
  const int n = min(cnt[t], CAP);

  for (int i = tid; i < CAP; i += 256) {
    u64 key = ~0ull;
    if (i < n) {
      u32 uk = fkey(cval[(size_t)t * CAP + i]);
      key = ((u64)(~uk) << 32) | (u32)cidx[(size_t)t * CAP + i];
    }
    keys[i] = key;
  }
  __syncthreads();
  for (int k = 2; k <= CAP; k <<= 1) {
    for (int j = k >> 1; j > 0; j >>= 1) {
      for (int i = tid; i < CAP; i += 256) {
        int ixj = i ^ j;
        if (ixj > i) {
          u64 a = keys[i], b = keys[ixj];
          if ((a > b) == ((i & k) == 0)) { keys[i] = b; keys[ixj] = a; }
        }
      }
      __syncthreads();
    }
  }
  if (tid < RSEL) fidx[tid] = (int)(u32)(keys[tid] & 0xFFFFFFFFull);
  __syncthreads();

  const float* er = encn + (size_t)t * PDIM + lane * 8;
  float4 e0 = *(const float4*)er;
  float4 e1 = *(const float4*)(er + 4);

  // fp32 rerank of coarse top-256: wave w -> [w*64, w*64+64), 4 in flight
  for (int c0 = w * 64; c0 < w * 64 + 64; c0 += 4) {
    int id[4]; float msk[4]; float4 p0[4], p1[4];
    #pragma unroll
    for (int u = 0; u < 4; ++u) {
      int iv = fidx[c0 + u];
      bool ok = ((u32)iv < (u32)NPAT);
      id[u] = ok ? iv : 0;
      msk[u] = ok ? 1.0f : 0.0f;
      const float* pr = pat + (size_t)id[u] * PDIM + lane * 8;
      p0[u] = *(const float4*)pr;
      p1[u] = *(const float4*)(pr + 4);
    }
    #pragma unroll
    for (int u = 0; u < 4; ++u) {
      float dd = p0[u].x*e0.x + p0[u].y*e0.y + p0[u].z*e0.z + p0[u].w*e0.w
               + p1[u].x*e1.x + p1[u].y*e1.y + p1[u].z*e1.z + p1[u].w*e1.w;
      #pragma unroll
      for (int m = 1; m < 64; m <<= 1) dd += __shfl_xor(dd, m);
      if (lane == 0) fs[c0 + u] = (msk[u] > 0.f) ? dd * prn[id[u]] : -1e30f;
    }
  }
  __syncthreads();

  {
    u64 key = ((u64)(~fkey(fs[tid])) << 32) | (u32)fidx[tid];
    keys2[tid] = key;
  }
  __syncthreads();
  for (int k = 2; k <= 256; k <<= 1) {
    for (int j = k >> 1; j > 0; j >>= 1) {
      int ixj = tid ^ j;
      if (ixj > tid) {
        u64 a = keys2[tid], b = keys2[ixj];
        if ((a > b) == ((tid & k) == 0)) { keys2[tid] = b; keys2[ixj] = a; }
      }
      __syncthreads();
    }
  }

  // sum the 128 winners: wave w -> [w*32, w*32+32), 4 in flight
  float4 s0 = {0,0,0,0}, s1 = {0,0,0,0};
  for (int c0 = w * 32; c0 < w * 32 + 32; c0 += 4) {
    int id[4]; float msk[4]; float4 p0[4], p1[4];
    #pragma unroll
    for (int u = 0; u < 4; ++u) {
      int iv = (int)(u32)(keys2[c0 + u] & 0xFFFFFFFFull);
      bool ok = ((u32)iv < (u32)NPAT);
      id[u] = ok ? iv : 0;
      msk[u] = ok ? 1.0f : 0.0f;
      const float* pr = pat + (size_t)id[u] * PDIM + lane * 8;
      p0[u] = *(const float4*)pr;
      p1[u] = *(const float4*)(pr + 4);
    }
    #pragma unroll
    for (int u = 0; u < 4; ++u) {
      s0.x += p0[u].x * msk[u]; s0.y += p0[u].y * msk[u];
      s0.z += p0[u].z * msk[u]; s0.w += p0[u].w * msk[u];
      s1.x += p1[u].x * msk[u]; s1.y += p1[u].y * msk[u];
      s1.z += p1[u].z * msk[u]; s1.w += p1[u].w * msk[u];
    }
  }
  *(float4*)&wsum[w][lane * 8]     = s0;
  *(float4*)&wsum[w][lane * 8 + 4] = s1;
  __syncthreads();
  for (int dd = tid; dd < PDIM; dd += 256) {
    float m = (wsum[0][dd] + wsum[1][dd] + wsum[2][dd] + wsum[3][dd]) * (1.0f / 128.0f);
    meanb[(size_t)t * PDIM + dd] = f2b(m);
  }
}

// ---- decoder (bf16 MFMA): out = x + alpha*(mean @ dec_w^T + dec_b) -----------
__global__ __launch_bounds__(256) void k_dec(const u16* __restrict__ A,
                                             const u16* __restrict__ B,
                                             const float* __restrict__ x,
                                             const float* __restrict__ alpha,
                                             const float* __restrict__ db,
                                             float* __restrict__ out) {
  __shared__ __align__(16) u16 As[128 * 32];
  __shared__ __align__(16) u16 Bs[128 * 32];
  const int bm = blockIdx.x, bn = blockIdx.y;
  const int tid = threadIdx.x, lane = tid & 63, w = tid >> 6;
  const int wm = w >> 1, wn = w & 1;
  f32x4 acc[4][4];
  #pragma unroll
  for (int i = 0; i < 4; ++i)
    #pragma unroll
    for (int j = 0; j < 4; ++j) acc[i][j] = (f32x4){0.f, 0.f, 0.f, 0.f};

  const int c0 = w * 2, c1 = w * 2 + 1;
  const int lrow = lane >> 2, lk = (lane & 3) * 8;
  const u16* gA0 = A + (size_t)(bm * 128 + c0 * 16 + lrow) * PDIM + lk;
  const u16* gA1 = A + (size_t)(bm * 128 + c1 * 16 + lrow) * PDIM + lk;
  const u16* gB0 = B + (size_t)(bn * 128 + c0 * 16 + lrow) * PDIM + lk;
  const u16* gB1 = B + (size_t)(bn * 128 + c1 * 16 + lrow) * PDIM + lk;
  u16* lA0 = &As[c0 * 512]; u16* lA1 = &As[c1 * 512];
  u16* lB0 = &Bs[c0 * 512]; u16* lB1 = &Bs[c1 * 512];
  const int fm = (lane & 15) * 32 + (lane >> 4) * 8;

  for (int kt = 0; kt < 16; ++kt) {
    gl2lds16(gA0 + kt * 32, lA0);
    gl2lds16(gA1 + kt * 32, lA1);
    gl2lds16(gB0 + kt * 32, lB0);
    gl2lds16(gB1 + kt * 32, lB1);
    __syncthreads();
    bf16x8 af[4], bf[4];
    #pragma unroll
    for (int i = 0; i < 4; ++i) {
      af[i] = *(const bf16x8*)&As[(wm * 64 + i * 16) * 32 + fm];
      bf[i] = *(const bf16x8*)&Bs[(wn * 64 + i * 16) * 32 + fm];
    }
    #pragma unroll
    for (int i = 0; i < 4; ++i)
      #pragma unroll
      for (int j = 0; j < 4; ++j)
        acc[i][j] = __builtin_amdgcn_mfma_f32_16x16x32_bf16(af[i], bf[j], acc[i][j], 0, 0, 0);
    __syncthreads();
  }

  const float al = alpha[0];
  #pragma unroll
  for (int i = 0; i < 4; ++i) {
    int tbase = bm * 128 + wm * 64 + i * 16 + ((lane >> 4) << 2);
    #pragma unroll
    for (int j = 0; j < 4; ++j) {
      int dcol = bn * 128 + wn * 64 + j * 16 + (lane & 15);
      float bias = db[dcol];
      #pragma unroll
      for (int r = 0; r < 4; ++r) {
        int tt = tbase + r;
        size_t oi = (size_t)tt * DDIM + dcol;
        out[oi] = x[oi] + al * (acc[i][j][r] + bias);
      }
    }
  }
}

extern "C" void kernel_launch(void* const* d_in, const int* in_sizes, int n_in,
                              void* d_out, int out_size, void* d_ws, size_t ws_size,
                              hipStream_t stream) {
  const float* x     = (const float*)d_in[0];
  const float* pat   = (const float*)d_in[1];
  const float* alpha = (const float*)d_in[2];
  const float* enc_w = (const float*)d_in[3];
  const float* enc_b = (const float*)d_in[4];
  const float* dec_w = (const float*)d_in[5];
  const float* dec_b = (const float*)d_in[6];
  float* out = (float*)d_out;

  char* wsb = (char*)d_ws;
  size_t o = 0;
  auto alloc = [&](size_t bytes) -> void* {
    void* p = wsb + o;
    o += (bytes + 255) & ~(size_t)255;
    return p;
  };
  unsigned char* pnf8  = (unsigned char*)alloc((size_t)NPAT * PDIM);      // 32 MB
  float* prn    = (float*)alloc((size_t)NPAT * 4);                        // 256 KB
  u16*   xh     = (u16*)  alloc((size_t)TOK * DDIM * 2);                  // 8 MB
  u16*   xl     = (u16*)  alloc((size_t)TOK * DDIM * 2);                  // 8 MB
  u16*   wh     = (u16*)  alloc((size_t)PDIM * DDIM * 2);                 // 1 MB
  u16*   wl     = (u16*)  alloc((size_t)PDIM * DDIM * 2);                 // 1 MB
  float* enc    = (float*)alloc((size_t)TOK * PDIM * 4);                  // 8 MB
  float* encn   = (float*)alloc((size_t)TOK * PDIM * 4);                  // 8 MB
  unsigned char* encf8 = (unsigned char*)alloc((size_t)TOK * PDIM);       // 2 MB
  int*   ccnt   = (int*)  alloc((size_t)TOK * 4);                         // 16 KB
  float* cvals  = (float*)alloc((size_t)TOK * CAP * 4);                   // 16 MB
  int*   cids   = (int*)  alloc((size_t)TOK * CAP * 4);                   // 16 MB
  u16*   meanb  = (u16*)  alloc((size_t)TOK * PDIM * 2);                  // 4 MB
  u16*   decwb  = (u16*)  alloc((size_t)DDIM * PDIM * 2);                 // 1 MB
  (void)ws_size; (void)in_sizes; (void)n_in; (void)out_size;

  k_patnorm<<<dim3(NPAT / 4), dim3(256), 0, stream>>>(pat, pnf8, prn);
  k_zero<<<dim3(TOK / 256), dim3(256), 0, stream>>>(ccnt, TOK);
  k_tobf16<<<dim3((DDIM * PDIM) / 256), dim3(256), 0, stream>>>(dec_w, decwb, DDIM * PDIM);
  k_split4<<<dim3((TOK * DDIM / 4) / 256), dim3(256), 0, stream>>>(x, xh, xl, TOK * DDIM / 4);
  k_split4<<<dim3((PDIM * DDIM / 4) / 256), dim3(256), 0, stream>>>(enc_w, wh, wl, PDIM * DDIM / 4);
  k_enc3<<<dim3(TOK / 64, PDIM / 128), dim3(256), 0, stream>>>(xh, xl, wh, wl, enc_b, enc);
  k_encnorm<<<dim3(TOK / 4), dim3(256), 0, stream>>>(enc, encn, encf8);
  k_sim<<<dim3(TOK / 128, 16), dim3(512), 0, stream>>>(encf8, pnf8, ccnt, cvals, cids);
  k_select<<<dim3(TOK), dim3(256), 0, stream>>>(pat, prn, encn, ccnt, cvals, cids, meanb);
  k_dec<<<dim3(TOK / 128, DDIM / 128), dim3(256), 0, stream>>>(meanb, decwb, x, alpha, dec_b, out);
}